// Round 5
// baseline (938.732 us; speedup 1.0000x reference)
//
#include <hip/hip_runtime.h>
#include <stdint.h>

typedef float f32x4 __attribute__((ext_vector_type(4)));
typedef short s16x8 __attribute__((ext_vector_type(8)));
typedef short s16x4 __attribute__((ext_vector_type(4)));

#define MFMA16(a, b, c) __builtin_amdgcn_mfma_f32_16x16x32_bf16(a, b, c, 0, 0, 0)

__device__ __forceinline__ unsigned short f2bf(float f) {
  union { float f; uint32_t u; } v; v.f = f;
  return (unsigned short)((v.u + 0x7FFFu + ((v.u >> 16) & 1u)) >> 16);
}
__device__ __forceinline__ float bf2f(unsigned short s) {
  union { float f; uint32_t u; } v; v.u = ((uint32_t)s) << 16;
  return v.f;
}
__device__ __forceinline__ s16x8 cvt8(const float* p) {
  f32x4 a = *(const f32x4*)p;
  f32x4 b = *(const f32x4*)(p + 4);
  s16x8 t;
  t[0] = (short)f2bf(a[0]); t[1] = (short)f2bf(a[1]);
  t[2] = (short)f2bf(a[2]); t[3] = (short)f2bf(a[3]);
  t[4] = (short)f2bf(b[0]); t[5] = (short)f2bf(b[1]);
  t[6] = (short)f2bf(b[2]); t[7] = (short)f2bf(b[3]);
  return t;
}

// ---------------------------------------------------------------------------
// Stage 1: Y = X @ W^T + b. W in LDS (verified R1); X double-buffered over t.
// ---------------------------------------------------------------------------
__global__ __launch_bounds__(256) void proj_kernel(
    const float* __restrict__ Xq, const float* __restrict__ Xk, const float* __restrict__ Xv,
    const float* __restrict__ Wq, const float* __restrict__ bq,
    const float* __restrict__ Wk, const float* __restrict__ bk,
    const float* __restrict__ Wv, const float* __restrict__ bv,
    unsigned short* __restrict__ Qt, unsigned short* __restrict__ Kt,
    unsigned short* __restrict__ Vf) {
  __shared__ unsigned char Wsh[32768];

  const int ty = blockIdx.y;
  const float* X = (ty == 0) ? Xq : (ty == 1) ? Xk : Xv;
  const float* W = (ty == 0) ? Wq : (ty == 1) ? Wk : Wv;
  const float* B = (ty == 0) ? bq : (ty == 1) ? bk : bv;
  unsigned short* out = (ty == 0) ? Qt : (ty == 1) ? Kt : Vf;
  const bool transposed = (ty != 2);

  const int tid = threadIdx.x;
  const int lane = tid & 63;
  const int wave = tid >> 6;
  const int l15 = lane & 15;
  const int g = lane >> 4;

  {
    const int r = tid >> 1;
    const int cb = (tid & 1) * 64;
    const float* wp = W + (size_t)r * 128 + cb;
#pragma unroll
    for (int c8 = 0; c8 < 8; ++c8) {
      s16x8 w = cvt8(wp + 8 * c8);
      const int byte = r * 256 + ((cb * 2 + c8 * 16) ^ ((r & 7) << 4));
      *(s16x8*)(Wsh + byte) = w;
    }
  }
  __syncthreads();

  auto wfrag = [&](int f, int kc) -> s16x8 {
    const int row = 16 * f + l15;
    return *(const s16x8*)(Wsh + row * 256 + ((64 * kc + 16 * g) ^ ((row & 7) << 4)));
  };

  if (transposed) {
    float bias_s[8];
#pragma unroll
    for (int f = 0; f < 8; ++f) bias_s[f] = B[16 * f + l15];

    auto loadX = [&](s16x8 (&xf)[4], int t) {
      const int jb = blockIdx.x * 512 + t * 64 + wave * 16;
      const int jrow = jb + (l15 >> 2) + 4 * (l15 & 3);
      const float* xr = X + (size_t)jrow * 128 + 8 * g;
#pragma unroll
      for (int kc = 0; kc < 4; ++kc) xf[kc] = cvt8(xr + 32 * kc);
    };
    auto computeStore = [&](s16x8 (&xf)[4], int t) {
      const int jb = blockIdx.x * 512 + t * 64 + wave * 16;
      f32x4 acc[8];
#pragma unroll
      for (int f = 0; f < 8; ++f) acc[f] = (f32x4){0.f, 0.f, 0.f, 0.f};
#pragma unroll
      for (int kc = 0; kc < 4; ++kc)
#pragma unroll
        for (int f = 0; f < 8; ++f) acc[f] = MFMA16(xf[kc], wfrag(f, kc), acc[f]);
      const int n = jb >> 9;
      const int c0 = (jb & 511) >> 2;
#pragma unroll
      for (int f = 0; f < 8; ++f) {
        const int h = 128 * g + 16 * f + l15;
        s16x4 pv;
#pragma unroll
        for (int r = 0; r < 4; ++r) pv[r] = (short)f2bf(acc[f][r] + bias_s[f]);
        *(s16x4*)(out + (size_t)n * 65536 + (size_t)h * 128 + c0) = pv;
      }
    };

    s16x8 xfA[4], xfB[4];
    loadX(xfA, 0);
#pragma unroll
    for (int t = 0; t < 8; ++t) {
      if ((t & 1) == 0) {
        if (t < 7) loadX(xfB, t + 1);
        computeStore(xfA, t);
      } else {
        if (t < 7) loadX(xfA, t + 1);
        computeStore(xfB, t);
      }
    }
  } else {
    f32x4 bias_v[8];
#pragma unroll
    for (int f = 0; f < 8; ++f) bias_v[f] = *(const f32x4*)(B + 16 * f + 4 * g);

    auto loadX = [&](s16x8 (&xf)[4], int t) {
      const int jb = blockIdx.x * 512 + t * 64 + wave * 16;
      const int jrow = jb + l15;
      const float* xr = X + (size_t)jrow * 128 + 8 * g;
#pragma unroll
      for (int kc = 0; kc < 4; ++kc) xf[kc] = cvt8(xr + 32 * kc);
    };
    auto computeStore = [&](s16x8 (&xf)[4], int t) {
      const int jb = blockIdx.x * 512 + t * 64 + wave * 16;
      f32x4 acc[8];
#pragma unroll
      for (int f = 0; f < 8; ++f) acc[f] = (f32x4){0.f, 0.f, 0.f, 0.f};
#pragma unroll
      for (int kc = 0; kc < 4; ++kc)
#pragma unroll
        for (int f = 0; f < 8; ++f) acc[f] = MFMA16(wfrag(f, kc), xf[kc], acc[f]);
      const int j = jb + l15;
#pragma unroll
      for (int f = 0; f < 8; ++f) {
        const int cc0 = 16 * f + 4 * g;
        s16x4 pv;
#pragma unroll
        for (int r = 0; r < 4; ++r) pv[r] = (short)f2bf(acc[f][r] + bias_v[f][r]);
        *(s16x4*)(out + (size_t)j * 128 + cc0) = pv;
      }
    };

    s16x8 xfA[4], xfB[4];
    loadX(xfA, 0);
#pragma unroll
    for (int t = 0; t < 8; ++t) {
      if ((t & 1) == 0) {
        if (t < 7) loadX(xfB, t + 1);
        computeStore(xfA, t);
      } else {
        if (t < 7) loadX(xfA, t + 1);
        computeStore(xfB, t);
      }
    }
  }
}

// ---------------------------------------------------------------------------
// Stage 2a (qk): S^T = K·Q^T (swapped operands, sigma-permuted K-row feed),
// exp, rowsum. Unnormalized P bf16 -> second half of each attn row
// (bytes 1024..2047); 1/rowsum -> out0[row][0]. Direct K loads (L2-shared),
// double-buffered chunks, no LDS, no barriers, independent waves.
// ---------------------------------------------------------------------------
__global__ __launch_bounds__(256, 4) void qk_kernel(
    const unsigned short* __restrict__ Qt, const unsigned short* __restrict__ Kt,
    unsigned short* __restrict__ Pout, float* __restrict__ out0) {
  const int tid = threadIdx.x;
  const int lane = tid & 63;
  const int wave = tid >> 6;
  const int l15 = lane & 15;
  const int g = lane >> 4;

  const int bid = blockIdx.x;
  const int nb = (bid & 7) * 512 + (bid >> 3);
  const int head = nb >> 3;
  const int h0 = (nb & 7) * 64;
  const float scale = 0.08838834764831845f;  // 1/sqrt(128)

  const size_t khead = (size_t)head * 65536;
  const unsigned short* qbase =
      Qt + khead + (size_t)(h0 + 16 * wave + l15) * 128 + 8 * g;
  s16x8 qf[4];
#pragma unroll
  for (int kc = 0; kc < 4; ++kc) qf[kc] = *(const s16x8*)(qbase + 32 * kc);

  const int sig = 8 * (l15 >> 2) + (l15 & 3);
  const unsigned short* kbase = Kt + khead + (size_t)sig * 128 + 8 * g;

  auto loadKc = [&](s16x8 (&kf)[4], int c) {
    const unsigned short* kp = kbase + (c >> 1) * 4096 + (c & 1) * 512;
#pragma unroll
    for (int kc = 0; kc < 4; ++kc) kf[kc] = *(const s16x8*)(kp + 32 * kc);
  };

  unsigned short* pbase =
      Pout + (size_t)head * 524288 + (size_t)(h0 + 16 * wave + l15) * 1024 + 512 + 8 * g;
  float rs = 0.f;

  s16x8 ka[4], kb[4];
  loadKc(ka, 0);
#pragma unroll
  for (int w = 0; w < 16; ++w) {
    loadKc(kb, 2 * w + 1);
    f32x4 sA = {0.f, 0.f, 0.f, 0.f};
#pragma unroll
    for (int kc = 0; kc < 4; ++kc) sA = MFMA16(ka[kc], qf[kc], sA);
    if (w < 15) loadKc(ka, 2 * w + 2);
    f32x4 sB = {0.f, 0.f, 0.f, 0.f};
#pragma unroll
    for (int kc = 0; kc < 4; ++kc) sB = MFMA16(kb[kc], qf[kc], sB);

    s16x8 fr;
#pragma unroll
    for (int r = 0; r < 4; ++r) {
      const float e = __expf(sA[r] * scale);
      rs += e;
      fr[r] = (short)f2bf(e);
    }
#pragma unroll
    for (int r = 0; r < 4; ++r) {
      const float e = __expf(sB[r] * scale);
      rs += e;
      fr[4 + r] = (short)f2bf(e);
    }
    *(s16x8*)(pbase + w * 32) = fr;
  }

  rs += __shfl_xor(rs, 16);
  rs += __shfl_xor(rs, 32);
  if (g == 0)
    out0[(size_t)head * 65536 + (size_t)(h0 + 16 * wave + l15) * 128] = 1.0f / rs;
}

// ---------------------------------------------------------------------------
// Stage 2b (pv): read P bf16 (attn second half) + inv; write normalized attn
// f32 (NT, full 128B row segments; window w clobbers only P already consumed
// >=1 iter earlier); PV with direct V loads (half-window pipeline); out0 (NT).
// ---------------------------------------------------------------------------
__global__ __launch_bounds__(256, 4) void pv_kernel(
    const unsigned short* __restrict__ Vf, float* attn, float* out0) {
  const int tid = threadIdx.x;
  const int lane = tid & 63;
  const int wave = tid >> 6;
  const int l15 = lane & 15;
  const int g = lane >> 4;

  const int bid = blockIdx.x;
  const int nb = (bid & 7) * 512 + (bid >> 3);
  const int head = nb >> 3;
  const int h0 = (nb & 7) * 64;

  const int row = h0 + 16 * wave + l15;
  const float invq = out0[(size_t)head * 65536 + (size_t)row * 128];

  const unsigned short* pb16 = (const unsigned short*)attn;
  const unsigned short* pbase =
      pb16 + (size_t)head * 524288 + (size_t)row * 1024 + 512 + 8 * g;
  float* ap = attn + (size_t)head * 262144 + (size_t)row * 512 + 8 * g;

  const unsigned short* vbase = Vf + (size_t)head * 65536 + (size_t)l15 * 512 + 8 * g;

  auto loadVh = [&](s16x8 (&vv)[4], int w, int half) {
    const unsigned short* vp = vbase + (size_t)(half * 4) * 8192 + w * 32;
#pragma unroll
    for (int fi = 0; fi < 4; ++fi) vv[fi] = *(const s16x8*)(vp + (size_t)fi * 8192);
  };

  f32x4 acc2[8];
#pragma unroll
  for (int f = 0; f < 8; ++f) acc2[f] = (f32x4){0.f, 0.f, 0.f, 0.f};

  s16x8 vA[4], vB[4];
  s16x8 pf0 = *(const s16x8*)(pbase);
  s16x8 pf1;
  loadVh(vA, 0, 0);

#pragma unroll
  for (int w = 0; w < 16; ++w) {
    if (w < 15) {
      if ((w & 1) == 0) pf1 = *(const s16x8*)(pbase + (w + 1) * 32);
      else pf0 = *(const s16x8*)(pbase + (w + 1) * 32);
    }
    const s16x8 pc = ((w & 1) == 0) ? pf0 : pf1;

    // normalized attn write (reads pc -> compiler waits for pc load here,
    // which orders it before the store that may clobber later P windows)
    f32x4 o0, o1;
#pragma unroll
    for (int r = 0; r < 4; ++r) {
      o0[r] = bf2f((unsigned short)pc[r]) * invq;
      o1[r] = bf2f((unsigned short)pc[4 + r]) * invq;
    }
    __builtin_nontemporal_store(o0, (f32x4*)(ap + w * 32));
    __builtin_nontemporal_store(o1, (f32x4*)(ap + w * 32 + 4));

    loadVh(vB, w, 1);
#pragma unroll
    for (int fi = 0; fi < 4; ++fi) acc2[fi] = MFMA16(pc, vA[fi], acc2[fi]);
    if (w < 15) loadVh(vA, w + 1, 0);
#pragma unroll
    for (int fi = 0; fi < 4; ++fi) acc2[4 + fi] = MFMA16(pc, vB[fi], acc2[4 + fi]);
  }

  float invm[4];
#pragma unroll
  for (int r = 0; r < 4; ++r) invm[r] = __shfl(invq, 4 * g + r);

  float* op = out0 + (size_t)head * 65536 + (size_t)(h0 + 16 * wave + 4 * g) * 128 + l15;
#pragma unroll
  for (int f = 0; f < 8; ++f)
#pragma unroll
    for (int r = 0; r < 4; ++r)
      __builtin_nontemporal_store(acc2[f][r] * invm[r], op + (size_t)r * 128 + f * 16);
}

extern "C" void kernel_launch(void* const* d_in, const int* in_sizes, int n_in,
                              void* d_out, int out_size, void* d_ws, size_t ws_size,
                              hipStream_t stream) {
  const float* q  = (const float*)d_in[0];
  const float* k  = (const float*)d_in[1];
  const float* v  = (const float*)d_in[2];
  const float* Wq = (const float*)d_in[3];
  const float* bq = (const float*)d_in[4];
  const float* Wk = (const float*)d_in[5];
  const float* bk = (const float*)d_in[6];
  const float* Wv = (const float*)d_in[7];
  const float* bv = (const float*)d_in[8];

  unsigned short* Qt = (unsigned short*)d_ws;       // 64 MiB
  unsigned short* Kt = Qt + 33554432;               // 64 MiB
  unsigned short* Vf = Kt + 33554432;               // 64 MiB
  float* out0 = (float*)d_out;                      // 33,554,432 fp32
  float* attn = out0 + 33554432;                    // 134,217,728 fp32

  dim3 pgrid(512, 3, 1);
  proj_kernel<<<pgrid, 256, 0, stream>>>(q, k, v, Wq, bq, Wk, bk, Wv, bv, Qt, Kt, Vf);
  qk_kernel<<<4096, 256, 0, stream>>>(Qt, Kt, (unsigned short*)attn, out0);
  pv_kernel<<<4096, 256, 0, stream>>>(Vf, attn, out0);
}

// Round 6
// 782.523 us; speedup vs baseline: 1.1996x; 1.1996x over previous
//
#include <hip/hip_runtime.h>
#include <stdint.h>

typedef float f32x4 __attribute__((ext_vector_type(4)));
typedef short s16x8 __attribute__((ext_vector_type(8)));
typedef short s16x4 __attribute__((ext_vector_type(4)));

#define MFMA16(a, b, c) __builtin_amdgcn_mfma_f32_16x16x32_bf16(a, b, c, 0, 0, 0)

__device__ __forceinline__ unsigned short f2bf(float f) {
  union { float f; uint32_t u; } v; v.f = f;
  return (unsigned short)((v.u + 0x7FFFu + ((v.u >> 16) & 1u)) >> 16);
}
__device__ __forceinline__ float bf2f(unsigned short s) {
  union { float f; uint32_t u; } v; v.u = ((uint32_t)s) << 16;
  return v.f;
}
__device__ __forceinline__ s16x8 cvt8(const float* p) {
  f32x4 a = *(const f32x4*)p;
  f32x4 b = *(const f32x4*)(p + 4);
  s16x8 t;
  t[0] = (short)f2bf(a[0]); t[1] = (short)f2bf(a[1]);
  t[2] = (short)f2bf(a[2]); t[3] = (short)f2bf(a[3]);
  t[4] = (short)f2bf(b[0]); t[5] = (short)f2bf(b[1]);
  t[6] = (short)f2bf(b[2]); t[7] = (short)f2bf(b[3]);
  return t;
}

// ---------------------------------------------------------------------------
// Stage 1: Y = X @ W^T + b. W in LDS (bf16, XOR-swizzled). Exact R3 version.
// ---------------------------------------------------------------------------
__global__ __launch_bounds__(256) void proj_kernel(
    const float* __restrict__ Xq, const float* __restrict__ Xk, const float* __restrict__ Xv,
    const float* __restrict__ Wq, const float* __restrict__ bq,
    const float* __restrict__ Wk, const float* __restrict__ bk,
    const float* __restrict__ Wv, const float* __restrict__ bv,
    unsigned short* __restrict__ Qt, unsigned short* __restrict__ Kt,
    unsigned short* __restrict__ Vf) {
  __shared__ unsigned char Wsh[32768];

  const int ty = blockIdx.y;
  const float* X = (ty == 0) ? Xq : (ty == 1) ? Xk : Xv;
  const float* W = (ty == 0) ? Wq : (ty == 1) ? Wk : Wv;
  const float* B = (ty == 0) ? bq : (ty == 1) ? bk : bv;
  unsigned short* out = (ty == 0) ? Qt : (ty == 1) ? Kt : Vf;
  const bool transposed = (ty != 2);

  const int tid = threadIdx.x;
  const int lane = tid & 63;
  const int wave = tid >> 6;
  const int l15 = lane & 15;
  const int g = lane >> 4;

  {
    const int r = tid >> 1;
    const int cb = (tid & 1) * 64;
    const float* wp = W + (size_t)r * 128 + cb;
#pragma unroll
    for (int c8 = 0; c8 < 8; ++c8) {
      s16x8 w = cvt8(wp + 8 * c8);
      const int byte = r * 256 + ((cb * 2 + c8 * 16) ^ ((r & 7) << 4));
      *(s16x8*)(Wsh + byte) = w;
    }
  }
  __syncthreads();

  auto wfrag = [&](int f, int kc) -> s16x8 {
    const int row = 16 * f + l15;
    return *(const s16x8*)(Wsh + row * 256 + ((64 * kc + 16 * g) ^ ((row & 7) << 4)));
  };

  if (transposed) {
    float bias_s[8];
#pragma unroll
    for (int f = 0; f < 8; ++f) bias_s[f] = B[16 * f + l15];

    for (int t = 0; t < 8; ++t) {
      const int jb = blockIdx.x * 512 + t * 64 + wave * 16;
      const int jrow = jb + (l15 >> 2) + 4 * (l15 & 3);
      const float* xr = X + (size_t)jrow * 128 + 8 * g;
      s16x8 xf[4];
#pragma unroll
      for (int kc = 0; kc < 4; ++kc) xf[kc] = cvt8(xr + 32 * kc);

      f32x4 acc[8];
#pragma unroll
      for (int f = 0; f < 8; ++f) acc[f] = (f32x4){0.f, 0.f, 0.f, 0.f};
#pragma unroll
      for (int kc = 0; kc < 4; ++kc)
#pragma unroll
        for (int f = 0; f < 8; ++f) acc[f] = MFMA16(xf[kc], wfrag(f, kc), acc[f]);

      const int n = jb >> 9;
      const int c0 = (jb & 511) >> 2;
#pragma unroll
      for (int f = 0; f < 8; ++f) {
        const int h = 128 * g + 16 * f + l15;
        s16x4 pv;
#pragma unroll
        for (int r = 0; r < 4; ++r) pv[r] = (short)f2bf(acc[f][r] + bias_s[f]);
        *(s16x4*)(out + (size_t)n * 65536 + (size_t)h * 128 + c0) = pv;
      }
    }
  } else {
    f32x4 bias_v[8];
#pragma unroll
    for (int f = 0; f < 8; ++f) bias_v[f] = *(const f32x4*)(B + 16 * f + 4 * g);

    for (int t = 0; t < 8; ++t) {
      const int jb = blockIdx.x * 512 + t * 64 + wave * 16;
      const int jrow = jb + l15;
      const float* xr = X + (size_t)jrow * 128 + 8 * g;
      s16x8 xf[4];
#pragma unroll
      for (int kc = 0; kc < 4; ++kc) xf[kc] = cvt8(xr + 32 * kc);

      f32x4 acc[8];
#pragma unroll
      for (int f = 0; f < 8; ++f) acc[f] = (f32x4){0.f, 0.f, 0.f, 0.f};
#pragma unroll
      for (int kc = 0; kc < 4; ++kc)
#pragma unroll
        for (int f = 0; f < 8; ++f) acc[f] = MFMA16(wfrag(f, kc), xf[kc], acc[f]);

      const int j = jb + l15;
#pragma unroll
      for (int f = 0; f < 8; ++f) {
        const int cc0 = 16 * f + 4 * g;
        s16x4 pv;
#pragma unroll
        for (int r = 0; r < 4; ++r) pv[r] = (short)f2bf(acc[f][r] + bias_v[f][r]);
        *(s16x4*)(out + (size_t)j * 128 + cc0) = pv;
      }
    }
  }
}

// ---------------------------------------------------------------------------
// Stage 2 (fused): per (head, 64-row Q-tile), 4 independent waves (16 rows
// each), NO barriers. Phase A: S^T = K·Q^T (sigma-permuted feed), exp,
// rowsum; P windows stashed in wave-private LDS (16KB/wave, lane-major,
// addr = wave*16K + w*1024 + lane*16). Phase B: per window, one ds_read
// serves both the normalized attn NT-store and the PV A-fragment; V
// double-buffered in registers. No P->HBM traffic, no aliasing anywhere.
// ---------------------------------------------------------------------------
__global__ __launch_bounds__(256) void fattn_kernel(
    const unsigned short* __restrict__ Qt, const unsigned short* __restrict__ Kt,
    const unsigned short* __restrict__ Vf, float* __restrict__ out0,
    float* __restrict__ attn_out) {
  __shared__ unsigned char Psh[65536];  // 4 waves x 16 KB, wave-private

  const int tid = threadIdx.x;
  const int lane = tid & 63;
  const int wave = tid >> 6;
  const int l15 = lane & 15;
  const int g = lane >> 4;

  const int bid = blockIdx.x;
  const int nb = (bid & 7) * 512 + (bid >> 3);
  const int head = nb >> 3;
  const int h0 = (nb & 7) * 64;
  const float scale = 0.08838834764831845f;  // 1/sqrt(128)

  const size_t khead = (size_t)head * 65536;
  const unsigned short* qbase =
      Qt + khead + (size_t)(h0 + 16 * wave + l15) * 128 + 8 * g;
  s16x8 qf[4];
#pragma unroll
  for (int kc = 0; kc < 4; ++kc) qf[kc] = *(const s16x8*)(qbase + 32 * kc);

  const int sig = 8 * (l15 >> 2) + (l15 & 3);
  const unsigned short* kbase = Kt + khead + (size_t)sig * 128 + 8 * g;

  auto loadKc = [&](s16x8 (&kf)[4], int c) {
    const unsigned short* kp = kbase + (c >> 1) * 4096 + (c & 1) * 512;
#pragma unroll
    for (int kc = 0; kc < 4; ++kc) kf[kc] = *(const s16x8*)(kp + 32 * kc);
  };

  unsigned char* myP = Psh + wave * 16384;
  float rs = 0.f;

  // ---- phase A: S^T -> exp -> stash windows in wave-private LDS ----
  {
    s16x8 ka[4], kb[4];
    loadKc(ka, 0);
#pragma unroll
    for (int w = 0; w < 16; ++w) {
      loadKc(kb, 2 * w + 1);
      f32x4 sA = {0.f, 0.f, 0.f, 0.f};
#pragma unroll
      for (int kc = 0; kc < 4; ++kc) sA = MFMA16(ka[kc], qf[kc], sA);
      if (w < 15) loadKc(ka, 2 * w + 2);
      f32x4 sB = {0.f, 0.f, 0.f, 0.f};
#pragma unroll
      for (int kc = 0; kc < 4; ++kc) sB = MFMA16(kb[kc], qf[kc], sB);

      s16x8 fr;
#pragma unroll
      for (int r = 0; r < 4; ++r) {
        const float e = __expf(sA[r] * scale);
        rs += e;
        fr[r] = (short)f2bf(e);
      }
#pragma unroll
      for (int r = 0; r < 4; ++r) {
        const float e = __expf(sB[r] * scale);
        rs += e;
        fr[4 + r] = (short)f2bf(e);
      }
      *(s16x8*)(myP + w * 1024 + lane * 16) = fr;
    }
  }

  // full rowsum for row l15 (combine the 4 g-partials)
  rs += __shfl_xor(rs, 16);
  rs += __shfl_xor(rs, 32);
  const float inv = 1.0f / rs;

  // ---- phase B: attn write + PV, V double-buffered ----
  f32x4 acc2[8];
#pragma unroll
  for (int f = 0; f < 8; ++f) acc2[f] = (f32x4){0.f, 0.f, 0.f, 0.f};

  const unsigned short* vbase = Vf + khead + (size_t)l15 * 512 + 8 * g;
  float* ap = attn_out + (size_t)head * 262144 + (size_t)(h0 + 16 * wave + l15) * 512 + 8 * g;

  auto loadVh = [&](s16x8 (&vv)[4], int w, int half) {
    const unsigned short* vp = vbase + (size_t)(half * 4) * 8192 + w * 32;
#pragma unroll
    for (int fi = 0; fi < 4; ++fi) vv[fi] = *(const s16x8*)(vp + (size_t)fi * 8192);
  };

  s16x8 vA[4], vB[4];
  loadVh(vA, 0, 0);

#pragma unroll
  for (int w = 0; w < 16; ++w) {
    const s16x8 pc = *(const s16x8*)(myP + w * 1024 + lane * 16);

    f32x4 o0, o1;
#pragma unroll
    for (int r = 0; r < 4; ++r) {
      o0[r] = bf2f((unsigned short)pc[r]) * inv;
      o1[r] = bf2f((unsigned short)pc[4 + r]) * inv;
    }
    __builtin_nontemporal_store(o0, (f32x4*)(ap + w * 32));
    __builtin_nontemporal_store(o1, (f32x4*)(ap + w * 32 + 4));

    loadVh(vB, w, 1);
#pragma unroll
    for (int fi = 0; fi < 4; ++fi) acc2[fi] = MFMA16(pc, vA[fi], acc2[fi]);
    if (w < 15) loadVh(vA, w + 1, 0);
#pragma unroll
    for (int fi = 0; fi < 4; ++fi) acc2[4 + fi] = MFMA16(pc, vB[fi], acc2[4 + fi]);
  }

  // ---- out0 (normalized, NT) ----
  float invm[4];
#pragma unroll
  for (int r = 0; r < 4; ++r) invm[r] = __shfl(inv, 4 * g + r);

  float* op = out0 + khead + (size_t)(h0 + 16 * wave + 4 * g) * 128 + l15;
#pragma unroll
  for (int f = 0; f < 8; ++f)
#pragma unroll
    for (int r = 0; r < 4; ++r)
      __builtin_nontemporal_store(acc2[f][r] * invm[r], op + (size_t)r * 128 + f * 16);
}

extern "C" void kernel_launch(void* const* d_in, const int* in_sizes, int n_in,
                              void* d_out, int out_size, void* d_ws, size_t ws_size,
                              hipStream_t stream) {
  const float* q  = (const float*)d_in[0];
  const float* k  = (const float*)d_in[1];
  const float* v  = (const float*)d_in[2];
  const float* Wq = (const float*)d_in[3];
  const float* bq = (const float*)d_in[4];
  const float* Wk = (const float*)d_in[5];
  const float* bk = (const float*)d_in[6];
  const float* Wv = (const float*)d_in[7];
  const float* bv = (const float*)d_in[8];

  unsigned short* Qt = (unsigned short*)d_ws;       // 64 MiB
  unsigned short* Kt = Qt + 33554432;               // 64 MiB
  unsigned short* Vf = Kt + 33554432;               // 64 MiB
  float* out0 = (float*)d_out;                      // 33,554,432 fp32
  float* attn = out0 + 33554432;                    // 134,217,728 fp32

  dim3 pgrid(512, 3, 1);
  proj_kernel<<<pgrid, 256, 0, stream>>>(q, k, v, Wq, bq, Wk, bk, Wv, bv, Qt, Kt, Vf);
  fattn_kernel<<<4096, 256, 0, stream>>>(Qt, Kt, Vf, out0, attn);
}